// Round 8
// baseline (559.274 us; speedup 1.0000x reference)
//
#include <hip/hip_runtime.h>
#include <math.h>

#define FD 128
#define CLS 40
#define BN_EPS 1e-5f
#define AS_STRIDE 136   // ushort stride: 272 B rows, 16B-aligned, 2-way bank aliasing only
#define TM 32           // 32-row tiles: 2x grid vs 64 -> 6 blocks/CU (TLP was the limiter)

typedef short short8 __attribute__((ext_vector_type(8)));
typedef float floatx4 __attribute__((ext_vector_type(4)));
typedef unsigned short ushort4v __attribute__((ext_vector_type(4)));
typedef unsigned short u16;
typedef unsigned int u32;

__device__ __forceinline__ u16 bf16_of(float v) {
    unsigned int u = __float_as_uint(v);
    unsigned int r = u + 0x7FFFu + ((u >> 16) & 1u);   // RNE
    return (u16)(r >> 16);
}
__device__ __forceinline__ float bf16f(u16 h) {
    return __uint_as_float(((unsigned int)h) << 16);
}
__device__ __forceinline__ float blo(u32 v) { return __uint_as_float(v << 16); }
__device__ __forceinline__ float bhi(u32 v) { return __uint_as_float(v & 0xFFFF0000u); }
__device__ __forceinline__ float hswish(float x) {
    return x * fminf(fmaxf(x + 3.0f, 0.0f), 6.0f) * (1.0f / 6.0f);
}

// ---------------------------------------------------------------------------
// CSR build: hist -> 3-pass parallel exclusive scan -> scatter
// ---------------------------------------------------------------------------
__global__ void hist_kernel(const int* __restrict__ dst, int* __restrict__ cnt, int E) {
    int e = blockIdx.x * 256 + threadIdx.x;
    if (e < E) atomicAdd(&cnt[dst[e]], 1);
}

__global__ __launch_bounds__(256) void scan_p1(const int* __restrict__ cnt,
                                               int* __restrict__ bsum, int Nn) {
    const int t = threadIdx.x, b = blockIdx.x;
    int i = b * 256 + t;
    int v = (i < Nn) ? cnt[i] : 0;
    #pragma unroll
    for (int o = 32; o; o >>= 1) v += __shfl_xor(v, o);
    __shared__ int ws[4];
    if ((t & 63) == 0) ws[t >> 6] = v;
    __syncthreads();
    if (t == 0) bsum[b] = ws[0] + ws[1] + ws[2] + ws[3];
}

__global__ __launch_bounds__(256) void scan_p2(int* __restrict__ bsum, int NB,
                                               int* __restrict__ offs, int Nn) {
    __shared__ int wsum[4];
    __shared__ int run_s;
    const int t = threadIdx.x, lane = t & 63, wid = t >> 6;
    if (t == 0) run_s = 0;
    __syncthreads();
    for (int base = 0; base < NB; base += 256) {
        int i = base + t;
        int v = (i < NB) ? bsum[i] : 0;
        int x = v;
        #pragma unroll
        for (int o = 1; o < 64; o <<= 1) {
            int y = __shfl_up(x, o);
            if (lane >= o) x += y;
        }
        if (lane == 63) wsum[wid] = x;
        __syncthreads();
        int pre = run_s;
        #pragma unroll
        for (int w = 0; w < 4; ++w) { if (w < wid) pre += wsum[w]; }
        if (i < NB) bsum[i] = pre + x - v;
        __syncthreads();
        if (t == 0) run_s += wsum[0] + wsum[1] + wsum[2] + wsum[3];
        __syncthreads();
    }
    if (t == 0) offs[Nn] = run_s;
}

__global__ __launch_bounds__(256) void scan_p3(const int* __restrict__ cnt,
                                               const int* __restrict__ bsum,
                                               int* __restrict__ offs,
                                               int* __restrict__ cursor, int Nn) {
    __shared__ int wsum[4];
    const int t = threadIdx.x, b = blockIdx.x, lane = t & 63, wid = t >> 6;
    int i = b * 256 + t;
    int v = (i < Nn) ? cnt[i] : 0;
    int x = v;
    #pragma unroll
    for (int o = 1; o < 64; o <<= 1) {
        int y = __shfl_up(x, o);
        if (lane >= o) x += y;
    }
    if (lane == 63) wsum[wid] = x;
    __syncthreads();
    int pre = bsum[b];
    #pragma unroll
    for (int w = 0; w < 4; ++w) { if (w < wid) pre += wsum[w]; }
    if (i < Nn) {
        int excl = pre + x - v;
        offs[i] = excl;
        cursor[i] = excl;
    }
}

__global__ void scatter_kernel(const int* __restrict__ src, const int* __restrict__ dst,
                               int* __restrict__ cursor, int* __restrict__ col, int E) {
    int e = blockIdx.x * 256 + threadIdx.x;
    if (e < E) {
        int p = atomicAdd(&cursor[dst[e]], 1);
        col[p] = src[e];
    }
}

// ---------------------------------------------------------------------------
// Weight prep: square W[k][n] -> bf16 hi/lo transposed [n][k] (32768-short slots).
// Wp2 [128][40] -> padded [48][128] (hi at +0, lo at +6144).
// Wg panels: [16][128] with row0 = Wg[k], rows 1..15 zero (hi at +0, lo at +2048).
// ---------------------------------------------------------------------------
__global__ void prep_weights(const float* __restrict__ Wt, const float* __restrict__ W1,
                             const float* __restrict__ W2, const float* __restrict__ Wp1,
                             const float* __restrict__ Wp2, const float* __restrict__ Wg,
                             u16* __restrict__ wbuf, int L) {
    const int m = blockIdx.y;
    const int id = blockIdx.x * 256 + threadIdx.x;
    const int nsq = 3 * L + 1;
    if (m < nsq) {
        u16* base = wbuf + (size_t)m * 32768;
        const float* src = (m < L) ? Wt + m * 16384
                         : (m < 2 * L) ? W1 + (m - L) * 16384
                         : (m < 3 * L) ? W2 + (m - 2 * L) * 16384
                         : Wp1;
        int n = id >> 7, k = id & 127;
        float v = src[k * 128 + n];
        u16 h = bf16_of(v);
        base[n * 128 + k] = h;
        base[16384 + n * 128 + k] = bf16_of(v - bf16f(h));
    } else if (m == nsq) {               // Wp2
        if (id >= 48 * 128) return;
        u16* base = wbuf + (size_t)m * 32768;
        int n = id >> 7, k = id & 127;
        float v = (n < CLS) ? Wp2[k * CLS + n] : 0.f;
        u16 h = bf16_of(v);
        base[n * 128 + k] = h;
        base[6144 + n * 128 + k] = bf16_of(v - bf16f(h));
    } else {                             // Wg panel, gi = m - (3L+2)
        int gi = m - (nsq + 1);
        if (id >= 2048) return;
        u16* base = wbuf + (size_t)(nsq + 1) * 32768 + (size_t)gi * 4096;
        float v = (id < 128) ? Wg[gi * 128 + id] : 0.f;
        u16 h = bf16_of(v);
        base[id] = h;
        base[2048 + id] = bf16_of(v - bf16f(h));
    }
}

// ---------------------------------------------------------------------------
// GEMM building blocks. Block tile 32 rows x 128 cols, K=128, 4 waves.
// COLUMN-split: wave w owns cols [32w, 32w+32); 16 B-fragments in registers
// for the whole GEMM -> 8 MFMAs per B-load. 2 row-tiles per wave (rt<2).
// A-frag: A[m=l16][k=quad*8+j]; C/D: row=rt*16+quad*4+reg, col=l16 (measured).
// ---------------------------------------------------------------------------
__device__ __forceinline__ void stage_f32(const float* __restrict__ A, int m0, int M,
                                          u16* As, int t) {
    #pragma unroll
    for (int i = 0; i < 4; ++i) {
        int id = i * 256 + t;
        int row = id >> 5, c4 = id & 31;
        float4 v = make_float4(0.f, 0.f, 0.f, 0.f);
        if (m0 + row < M) v = ((const float4*)A)[(size_t)(m0 + row) * 32 + c4];
        ushort4v hh = {bf16_of(v.x), bf16_of(v.y), bf16_of(v.z), bf16_of(v.w)};
        *(ushort4v*)(&As[row * AS_STRIDE + c4 * 4]) = hh;
    }
}

__device__ __forceinline__ void stage_bf16(const u16* __restrict__ A, int m0, int M,
                                           u16* As, int t) {
    #pragma unroll
    for (int i = 0; i < 2; ++i) {
        int id = i * 256 + t;
        int row = id >> 4, c8 = id & 15;
        short8 v = {0, 0, 0, 0, 0, 0, 0, 0};
        if (m0 + row < M) v = ((const short8*)A)[(size_t)(m0 + row) * 16 + c8];
        *(short8*)(&As[row * AS_STRIDE + c8 * 8]) = v;
    }
}

struct Bfrags { short8 h[2][4], l[2][4]; };   // [ct][kc], 64 VGPRs

__device__ __forceinline__ void load_B(const u16* __restrict__ Bh, const u16* __restrict__ Bl,
                                       int ct0, int l16, int quad, Bfrags& f) {
    #pragma unroll
    for (int c = 0; c < 2; ++c)
        #pragma unroll
        for (int kc = 0; kc < 4; ++kc) {
            int boff = ((ct0 + c) * 16 + l16) * 128 + kc * 32 + quad * 8;
            f.h[c][kc] = *(const short8*)(&Bh[boff]);
            f.l[c][kc] = *(const short8*)(&Bl[boff]);
        }
}

__device__ __forceinline__ void gemm_ct2(const u16* As, const Bfrags& f, int l16, int quad,
                                         floatx4 (&acc)[2][2]) {
    #pragma unroll
    for (int kc = 0; kc < 4; ++kc) {
        short8 a[2];
        #pragma unroll
        for (int rt = 0; rt < 2; ++rt)
            a[rt] = *(const short8*)(&As[(rt * 16 + l16) * AS_STRIDE + kc * 32 + quad * 8]);
        #pragma unroll
        for (int rt = 0; rt < 2; ++rt)
            #pragma unroll
            for (int c = 0; c < 2; ++c) {
                acc[rt][c] = __builtin_amdgcn_mfma_f32_16x16x32_bf16(a[rt], f.h[c][kc], acc[rt][c], 0, 0, 0);
                acc[rt][c] = __builtin_amdgcn_mfma_f32_16x16x32_bf16(a[rt], f.l[c][kc], acc[rt][c], 0, 0, 0);
            }
    }
}

#define ZERO_ACC(acc) { _Pragma("unroll") for (int rt = 0; rt < 2; ++rt) \
    { acc[rt][0] = (floatx4){0.f,0.f,0.f,0.f}; acc[rt][1] = (floatx4){0.f,0.f,0.f,0.f}; } }

// gate panel (16x128, only col 0 nonzero) on wave 0; writes gate rows
__device__ __forceinline__ void gate_panel(const u16* As, const u16* __restrict__ Gh,
                                           const u16* __restrict__ Gl,
                                           const float* __restrict__ bg,
                                           float* __restrict__ gate,
                                           int m0, int M, int l16, int quad) {
    floatx4 gacc[2];
    #pragma unroll
    for (int rt = 0; rt < 2; ++rt) gacc[rt] = (floatx4){0.f, 0.f, 0.f, 0.f};
    #pragma unroll
    for (int kc = 0; kc < 4; ++kc) {
        int boff = l16 * 128 + kc * 32 + quad * 8;
        short8 gh = *(const short8*)(&Gh[boff]);
        short8 gl = *(const short8*)(&Gl[boff]);
        #pragma unroll
        for (int rt = 0; rt < 2; ++rt) {
            short8 a = *(const short8*)(&As[(rt * 16 + l16) * AS_STRIDE + kc * 32 + quad * 8]);
            gacc[rt] = __builtin_amdgcn_mfma_f32_16x16x32_bf16(a, gh, gacc[rt], 0, 0, 0);
            gacc[rt] = __builtin_amdgcn_mfma_f32_16x16x32_bf16(a, gl, gacc[rt], 0, 0, 0);
        }
    }
    if (l16 == 0) {
        float b0 = bg[0];
        #pragma unroll
        for (int rt = 0; rt < 2; ++rt)
            #pragma unroll
            for (int reg = 0; reg < 4; ++reg) {
                int row = m0 + rt * 16 + quad * 4 + reg;
                if (row < M) gate[row] = gacc[rt][reg] + b0;
            }
    }
}

// ---------------------------------------------------------------------------
// Layer-0 entry: ht(bf16) = x @ Wt + bt ; gate = x @ Wg + bg   (x is f32)
// ---------------------------------------------------------------------------
__global__ __launch_bounds__(256, 4) void gemm_gate_kernel(
    const float* __restrict__ Af,
    const u16* __restrict__ Gh, const u16* __restrict__ Gl, const float* __restrict__ bg,
    const u16* __restrict__ Bh, const u16* __restrict__ Bl, const float* __restrict__ bt,
    u16* __restrict__ ht, float* __restrict__ gate, int M) {
    __shared__ __align__(16) u16 As[TM * AS_STRIDE];
    const int t = threadIdx.x, m0 = blockIdx.x * TM;
    const int w = t >> 6, lane = t & 63, l16 = lane & 15, quad = lane >> 4, ct0 = w * 2;
    Bfrags f;
    load_B(Bh, Bl, ct0, l16, quad, f);   // in flight during staging
    stage_f32(Af, m0, M, As, t);
    __syncthreads();
    floatx4 acc[2][2];
    ZERO_ACC(acc);
    gemm_ct2(As, f, l16, quad, acc);
    if (w == 0) gate_panel(As, Gh, Gl, bg, gate, m0, M, l16, quad);
    #pragma unroll
    for (int c = 0; c < 2; ++c) {
        int cc = (ct0 + c) * 16 + l16;
        float b = bt[cc];
        #pragma unroll
        for (int rt = 0; rt < 2; ++rt)
            #pragma unroll
            for (int reg = 0; reg < 4; ++reg) {
                int row = m0 + rt * 16 + quad * 4 + reg;
                if (row < M) ht[(size_t)row * 128 + cc] = bf16_of(acc[rt][c][reg] + b);
            }
    }
}

// ---------------------------------------------------------------------------
// Attention aggregation: one wave per dst node; ht rows bf16; out packed bf16.
// Edge loop unrolled x8 for memory-level parallelism (latency-bound gather).
// ---------------------------------------------------------------------------
__global__ __launch_bounds__(256) void agg_kernel(const float* __restrict__ gate,
                                                  const u32* __restrict__ ht32,
                                                  const int* __restrict__ offs,
                                                  const int* __restrict__ col,
                                                  u32* __restrict__ aggb, int Nn) {
    int gt = blockIdx.x * 256 + threadIdx.x;
    int n = gt >> 6, lane = gt & 63;
    if (n >= Nn) return;
    int beg = offs[n], end = offs[n + 1];
    float gs = gate[n];
    float m = gs;
    for (int e = beg + lane; e < end; e += 64) m = fmaxf(m, gate[col[e]]);
    #pragma unroll
    for (int o = 32; o; o >>= 1) m = fmaxf(m, __shfl_xor(m, o));
    float wself = __expf(gs - m);
    float denom0 = wself, denom1 = 0.f;
    u32 sv = ht32[(size_t)n * 64 + lane];
    float a0 = wself * blo(sv), a1 = wself * bhi(sv);
    float b0 = 0.f, b1 = 0.f;
    int e = beg;
    for (; e + 8 <= end; e += 8) {
        int c[8];
        #pragma unroll
        for (int j = 0; j < 8; ++j) c[j] = col[e + j];
        float g[8];
        #pragma unroll
        for (int j = 0; j < 8; ++j) g[j] = gate[c[j]];
        u32 v[8];
        #pragma unroll
        for (int j = 0; j < 8; ++j) v[j] = ht32[(size_t)c[j] * 64 + lane];
        float wj[8];
        #pragma unroll
        for (int j = 0; j < 8; ++j) wj[j] = __expf(g[j] - m);
        denom0 += (wj[0] + wj[1]) + (wj[2] + wj[3]);
        denom1 += (wj[4] + wj[5]) + (wj[6] + wj[7]);
        #pragma unroll
        for (int j = 0; j < 4; ++j) {
            a0 += wj[j] * blo(v[j]);
            a1 += wj[j] * bhi(v[j]);
        }
        #pragma unroll
        for (int j = 4; j < 8; ++j) {
            b0 += wj[j] * blo(v[j]);
            b1 += wj[j] * bhi(v[j]);
        }
    }
    for (; e < end; ++e) {
        int c = col[e];
        float w = __expf(gate[c] - m);
        u32 v = ht32[(size_t)c * 64 + lane];
        denom0 += w;
        a0 += w * blo(v);
        a1 += w * bhi(v);
    }
    float inv = 1.0f / (denom0 + denom1);
    float r0 = (a0 + b0) * inv, r1 = (a1 + b1) * inv;
    aggb[(size_t)n * 64 + lane] = (u32)bf16_of(r0) | ((u32)bf16_of(r1) << 16);
}

// ---------------------------------------------------------------------------
// Mid-layer mega kernel: agg -> h (W1/BN/hswish, W2/hswish) -> next layer's
// ht = h @ Wt' + bt' and gate = h @ Wg' + bg'. h never touches global.
// Phases: GEMM1(As->Zs), GEMM2(Zs->As=h), GEMM3(As->htb) + gate panel.
// ---------------------------------------------------------------------------
__global__ __launch_bounds__(256, 4) void layer_mid_kernel(
    const u16* __restrict__ A,
    const u16* __restrict__ B1h, const u16* __restrict__ B1l, const float* __restrict__ b1,
    const float* __restrict__ bng, const float* __restrict__ bnb,
    const float* __restrict__ bnm, const float* __restrict__ bnv,
    const u16* __restrict__ B2h, const u16* __restrict__ B2l, const float* __restrict__ b2,
    const u16* __restrict__ Wth, const u16* __restrict__ Wtl, const float* __restrict__ bt,
    const u16* __restrict__ Gh, const u16* __restrict__ Gl, const float* __restrict__ bg,
    u16* __restrict__ htb, float* __restrict__ gate, int M) {
    __shared__ __align__(16) u16 As[TM * AS_STRIDE];
    __shared__ __align__(16) u16 Zs[TM * AS_STRIDE];
    const int t = threadIdx.x, m0 = blockIdx.x * TM;
    const int w = t >> 6, lane = t & 63, l16 = lane & 15, quad = lane >> 4, ct0 = w * 2;
    Bfrags f;
    load_B(B1h, B1l, ct0, l16, quad, f);   // in flight during staging
    stage_bf16(A, m0, M, As, t);
    __syncthreads();
    floatx4 acc[2][2];
    ZERO_ACC(acc);
    gemm_ct2(As, f, l16, quad, acc);
    // z = hswish(BN(acc+b1)) -> Zs
    #pragma unroll
    for (int c = 0; c < 2; ++c) {
        int cc = (ct0 + c) * 16 + l16;
        float sc = bng[cc] * rsqrtf(bnv[cc] + BN_EPS);
        float sh = bnb[cc] - bnm[cc] * sc;
        float bb = b1[cc];
        #pragma unroll
        for (int rt = 0; rt < 2; ++rt)
            #pragma unroll
            for (int reg = 0; reg < 4; ++reg) {
                int r = rt * 16 + quad * 4 + reg;
                Zs[r * AS_STRIDE + cc] = bf16_of(hswish((acc[rt][c][reg] + bb) * sc + sh));
            }
    }
    load_B(B2h, B2l, ct0, l16, quad, f);
    __syncthreads();            // Zs complete; As reads complete -> As reusable
    ZERO_ACC(acc);
    gemm_ct2(Zs, f, l16, quad, acc);
    // h = hswish(acc+b2) -> As (bf16)
    #pragma unroll
    for (int c = 0; c < 2; ++c) {
        int cc = (ct0 + c) * 16 + l16;
        float b = b2[cc];
        #pragma unroll
        for (int rt = 0; rt < 2; ++rt)
            #pragma unroll
            for (int reg = 0; reg < 4; ++reg) {
                int r = rt * 16 + quad * 4 + reg;
                As[r * AS_STRIDE + cc] = bf16_of(hswish(acc[rt][c][reg] + b));
            }
    }
    load_B(Wth, Wtl, ct0, l16, quad, f);
    __syncthreads();            // h tile complete in As
    ZERO_ACC(acc);
    gemm_ct2(As, f, l16, quad, acc);
    if (w == 0) gate_panel(As, Gh, Gl, bg, gate, m0, M, l16, quad);
    #pragma unroll
    for (int c = 0; c < 2; ++c) {
        int cc = (ct0 + c) * 16 + l16;
        float b = bt[cc];
        #pragma unroll
        for (int rt = 0; rt < 2; ++rt)
            #pragma unroll
            for (int reg = 0; reg < 4; ++reg) {
                int row = m0 + rt * 16 + quad * 4 + reg;
                if (row < M) htb[(size_t)row * 128 + cc] = bf16_of(acc[rt][c][reg] + b);
            }
    }
}

// ---------------------------------------------------------------------------
// Final-layer mega kernel: agg -> h -> head: z' = hswish(h@Wp1+bp1),
// logits = z'@Wp2+bp2, out = log_softmax(logits).
// ---------------------------------------------------------------------------
__global__ __launch_bounds__(256, 4) void layer_final_kernel(
    const u16* __restrict__ A,
    const u16* __restrict__ B1h, const u16* __restrict__ B1l, const float* __restrict__ b1,
    const float* __restrict__ bng, const float* __restrict__ bnb,
    const float* __restrict__ bnm, const float* __restrict__ bnv,
    const u16* __restrict__ B2h, const u16* __restrict__ B2l, const float* __restrict__ b2,
    const u16* __restrict__ P1h, const u16* __restrict__ P1l, const float* __restrict__ bp1,
    const u16* __restrict__ P2h, const u16* __restrict__ P2l, const float* __restrict__ bp2,
    float* __restrict__ out, int M) {
    __shared__ __align__(16) u16 As[TM * AS_STRIDE];
    __shared__ __align__(16) u16 Zs[TM * AS_STRIDE];
    const int t = threadIdx.x, m0 = blockIdx.x * TM;
    const int w = t >> 6, lane = t & 63, l16 = lane & 15, quad = lane >> 4, ct0 = w * 2;
    Bfrags f;
    load_B(B1h, B1l, ct0, l16, quad, f);
    stage_bf16(A, m0, M, As, t);
    __syncthreads();
    floatx4 acc[2][2];
    ZERO_ACC(acc);
    gemm_ct2(As, f, l16, quad, acc);
    #pragma unroll
    for (int c = 0; c < 2; ++c) {
        int cc = (ct0 + c) * 16 + l16;
        float sc = bng[cc] * rsqrtf(bnv[cc] + BN_EPS);
        float sh = bnb[cc] - bnm[cc] * sc;
        float bb = b1[cc];
        #pragma unroll
        for (int rt = 0; rt < 2; ++rt)
            #pragma unroll
            for (int reg = 0; reg < 4; ++reg) {
                int r = rt * 16 + quad * 4 + reg;
                Zs[r * AS_STRIDE + cc] = bf16_of(hswish((acc[rt][c][reg] + bb) * sc + sh));
            }
    }
    load_B(B2h, B2l, ct0, l16, quad, f);
    __syncthreads();
    ZERO_ACC(acc);
    gemm_ct2(Zs, f, l16, quad, acc);
    // h = hswish(acc+b2) -> As
    #pragma unroll
    for (int c = 0; c < 2; ++c) {
        int cc = (ct0 + c) * 16 + l16;
        float b = b2[cc];
        #pragma unroll
        for (int rt = 0; rt < 2; ++rt)
            #pragma unroll
            for (int reg = 0; reg < 4; ++reg) {
                int r = rt * 16 + quad * 4 + reg;
                As[r * AS_STRIDE + cc] = bf16_of(hswish(acc[rt][c][reg] + b));
            }
    }
    load_B(P1h, P1l, ct0, l16, quad, f);
    __syncthreads();
    ZERO_ACC(acc);
    gemm_ct2(As, f, l16, quad, acc);
    // z' = hswish(acc+bp1) -> Zs
    #pragma unroll
    for (int c = 0; c < 2; ++c) {
        int cc = (ct0 + c) * 16 + l16;
        float bb = bp1[cc];
        #pragma unroll
        for (int rt = 0; rt < 2; ++rt)
            #pragma unroll
            for (int reg = 0; reg < 4; ++reg) {
                int r = rt * 16 + quad * 4 + reg;
                Zs[r * AS_STRIDE + cc] = bf16_of(hswish(acc[rt][c][reg] + bb));
            }
    }
    __syncthreads();
    // head GEMM2 row-split: wave w owns rows [8w, 8w+8) of 32, all 3 col-tiles
    const int wr0 = w * 8;
    floatx4 acc2[3];
    #pragma unroll
    for (int ct = 0; ct < 3; ++ct) acc2[ct] = (floatx4){0.f, 0.f, 0.f, 0.f};
    // rows wr0..wr0+7 live in l16 slots 0..7 of a 16-row MFMA; use l16&7 rows,
    // compute a full 16-row MFMA but only rows wr0..wr0+7 of Zs (pad by reuse).
    #pragma unroll
    for (int kc = 0; kc < 4; ++kc) {
        int zr = wr0 + (l16 & 7);         // 8 distinct rows, duplicated twice
        short8 a = *(const short8*)(&Zs[zr * AS_STRIDE + kc * 32 + quad * 8]);
        #pragma unroll
        for (int ct = 0; ct < 3; ++ct) {
            int boff = (ct * 16 + l16) * 128 + kc * 32 + quad * 8;
            short8 bh = *(const short8*)(&P2h[boff]);
            short8 bl = *(const short8*)(&P2l[boff]);
            acc2[ct] = __builtin_amdgcn_mfma_f32_16x16x32_bf16(a, bh, acc2[ct], 0, 0, 0);
            acc2[ct] = __builtin_amdgcn_mfma_f32_16x16x32_bf16(a, bl, acc2[ct], 0, 0, 0);
        }
    }
    // C rows 0..15 map to A rows; rows 8..15 duplicate 0..7 (same data) — use rows 0..7 + wr0
    #pragma unroll
    for (int reg = 0; reg < 4; ++reg) {
        int crow = quad * 4 + reg;        // 0..15
        if (crow >= 8) continue;          // duplicate half
        float v[3];
        #pragma unroll
        for (int ct = 0; ct < 3; ++ct) {
            int c = ct * 16 + l16;
            v[ct] = (c < CLS) ? acc2[ct][reg] + bp2[c] : -INFINITY;
        }
        float mx = fmaxf(fmaxf(v[0], v[1]), v[2]);
        #pragma unroll
        for (int o = 1; o < 16; o <<= 1) mx = fmaxf(mx, __shfl_xor(mx, o));
        float s = 0.f;
        #pragma unroll
        for (int ct = 0; ct < 3; ++ct) s += (v[ct] > -INFINITY) ? __expf(v[ct] - mx) : 0.f;
        #pragma unroll
        for (int o = 1; o < 16; o <<= 1) s += __shfl_xor(s, o);
        float lse = mx + __logf(s);
        int row = m0 + wr0 + crow;
        if (row < M) {
            #pragma unroll
            for (int ct = 0; ct < 3; ++ct) {
                int c = ct * 16 + l16;
                if (c < CLS) out[(size_t)row * CLS + c] = v[ct] - lse;
            }
        }
    }
}

// ---------------------------------------------------------------------------
extern "C" void kernel_launch(void* const* d_in, const int* in_sizes, int n_in,
                              void* d_out, int out_size, void* d_ws, size_t ws_size,
                              hipStream_t stream) {
    const float* x   = (const float*)d_in[0];
    const int*   src = (const int*)d_in[1];
    const int*   dst = (const int*)d_in[2];
    const float* Wg  = (const float*)d_in[3];
    const float* bg  = (const float*)d_in[4];
    const float* Wt  = (const float*)d_in[5];
    const float* bt  = (const float*)d_in[6];
    const float* W1  = (const float*)d_in[7];
    const float* b1  = (const float*)d_in[8];
    const float* bng = (const float*)d_in[9];
    const float* bnb = (const float*)d_in[10];
    const float* bnm = (const float*)d_in[11];
    const float* bnv = (const float*)d_in[12];
    const float* W2  = (const float*)d_in[13];
    const float* b2  = (const float*)d_in[14];
    const float* Wp1 = (const float*)d_in[15];
    const float* bp1 = (const float*)d_in[16];
    const float* Wp2 = (const float*)d_in[17];
    const float* bp2 = (const float*)d_in[18];
    float* out = (float*)d_out;

    const int N = in_sizes[0] / FD;
    const int E = in_sizes[1];
    const int L = in_sizes[3] / FD;
    const int nsq = 3 * L + 1;
    const int NB = (N + 255) / 256;

    u16* htb    = (u16*)d_ws;                          // N*128 bf16
    u16* aggb   = htb + (size_t)N * FD;                // N*128 bf16 (packed u32/lane)
    float* gate = (float*)(aggb + (size_t)N * FD);     // N
    u16* wbuf   = (u16*)(gate + N);
    size_t wslots = (size_t)(nsq + 1) * 32768 + (size_t)L * 4096;
    int* counts = (int*)(wbuf + wslots);
    int* offs   = counts + N;
    int* cursor = offs + (N + 1);
    int* col    = cursor + N;
    int* bsum   = col + E;

    // CSR build + weight split (static inputs, ws re-poisoned each call)
    hipMemsetAsync(counts, 0, N * sizeof(int), stream);
    hist_kernel<<<(E + 255) / 256, 256, 0, stream>>>(dst, counts, E);
    prep_weights<<<dim3(64, nsq + 1 + L), 256, 0, stream>>>(Wt, W1, W2, Wp1, Wp2, Wg, wbuf, L);
    scan_p1<<<NB, 256, 0, stream>>>(counts, bsum, N);
    scan_p2<<<1, 256, 0, stream>>>(bsum, NB, offs, N);
    scan_p3<<<NB, 256, 0, stream>>>(counts, bsum, offs, cursor, N);
    scatter_kernel<<<(E + 255) / 256, 256, 0, stream>>>(src, dst, cursor, col, E);

    const int grid_g = (N + TM - 1) / TM;
    const int wave_grid = (N + 3) / 4;

    u16* gp0 = wbuf + (size_t)(nsq + 1) * 32768;
    u16* wt0 = wbuf;
    gemm_gate_kernel<<<grid_g, 256, 0, stream>>>(x, gp0, gp0 + 2048, bg,
                                                 wt0, wt0 + 16384, bt, htb, gate, N);
    for (int i = 0; i < L; ++i) {
        agg_kernel<<<wave_grid, 256, 0, stream>>>(gate, (const u32*)htb,
                                                  offs, col, (u32*)aggb, N);
        u16* w1 = wbuf + (size_t)(L + i) * 32768;
        u16* w2 = wbuf + (size_t)(2 * L + i) * 32768;
        if (i < L - 1) {
            u16* wtn = wbuf + (size_t)(i + 1) * 32768;
            u16* gpn = wbuf + (size_t)(nsq + 1) * 32768 + (size_t)(i + 1) * 4096;
            layer_mid_kernel<<<grid_g, 256, 0, stream>>>(aggb,
                w1, w1 + 16384, b1 + i * FD,
                bng + i * FD, bnb + i * FD, bnm + i * FD, bnv + i * FD,
                w2, w2 + 16384, b2 + i * FD,
                wtn, wtn + 16384, bt + (i + 1) * FD,
                gpn, gpn + 2048, bg + (i + 1),
                htb, gate, N);
        } else {
            u16* wp1 = wbuf + (size_t)(3 * L) * 32768;
            u16* wp2 = wbuf + (size_t)nsq * 32768;
            layer_final_kernel<<<grid_g, 256, 0, stream>>>(aggb,
                w1, w1 + 16384, b1 + i * FD,
                bng + i * FD, bnb + i * FD, bnm + i * FD, bnv + i * FD,
                w2, w2 + 16384, b2 + i * FD,
                wp1, wp1 + 16384, bp1,
                wp2, wp2 + 6144, bp2,
                out, N);
        }
    }
}

// Round 9
// 464.480 us; speedup vs baseline: 1.2041x; 1.2041x over previous
//
#include <hip/hip_runtime.h>
#include <math.h>

#define FD 128
#define CLS 40
#define BN_EPS 1e-5f
#define AS_STRIDE 136   // ushort stride: 272 B rows, 16B-aligned, 2-way bank aliasing only
// TM=64 (R8's TM=32 regressed: B-reuse per block beats occupancy). Single-bf16
// B panels (no lo term): absmax margin 4.8x allows it; halves MFMA + B traffic.

typedef short short8 __attribute__((ext_vector_type(8)));
typedef float floatx4 __attribute__((ext_vector_type(4)));
typedef unsigned short ushort4v __attribute__((ext_vector_type(4)));
typedef unsigned short u16;
typedef unsigned int u32;

__device__ __forceinline__ u16 bf16_of(float v) {
    unsigned int u = __float_as_uint(v);
    unsigned int r = u + 0x7FFFu + ((u >> 16) & 1u);   // RNE
    return (u16)(r >> 16);
}
__device__ __forceinline__ float bf16f(u16 h) {
    return __uint_as_float(((unsigned int)h) << 16);
}
__device__ __forceinline__ float blo(u32 v) { return __uint_as_float(v << 16); }
__device__ __forceinline__ float bhi(u32 v) { return __uint_as_float(v & 0xFFFF0000u); }
__device__ __forceinline__ float hswish(float x) {
    return x * fminf(fmaxf(x + 3.0f, 0.0f), 6.0f) * (1.0f / 6.0f);
}

// ---------------------------------------------------------------------------
// CSR build: hist -> 3-pass parallel exclusive scan -> scatter
// ---------------------------------------------------------------------------
__global__ void hist_kernel(const int* __restrict__ dst, int* __restrict__ cnt, int E) {
    int e = blockIdx.x * 256 + threadIdx.x;
    if (e < E) atomicAdd(&cnt[dst[e]], 1);
}

__global__ __launch_bounds__(256) void scan_p1(const int* __restrict__ cnt,
                                               int* __restrict__ bsum, int Nn) {
    const int t = threadIdx.x, b = blockIdx.x;
    int i = b * 256 + t;
    int v = (i < Nn) ? cnt[i] : 0;
    #pragma unroll
    for (int o = 32; o; o >>= 1) v += __shfl_xor(v, o);
    __shared__ int ws[4];
    if ((t & 63) == 0) ws[t >> 6] = v;
    __syncthreads();
    if (t == 0) bsum[b] = ws[0] + ws[1] + ws[2] + ws[3];
}

__global__ __launch_bounds__(256) void scan_p2(int* __restrict__ bsum, int NB,
                                               int* __restrict__ offs, int Nn) {
    __shared__ int wsum[4];
    __shared__ int run_s;
    const int t = threadIdx.x, lane = t & 63, wid = t >> 6;
    if (t == 0) run_s = 0;
    __syncthreads();
    for (int base = 0; base < NB; base += 256) {
        int i = base + t;
        int v = (i < NB) ? bsum[i] : 0;
        int x = v;
        #pragma unroll
        for (int o = 1; o < 64; o <<= 1) {
            int y = __shfl_up(x, o);
            if (lane >= o) x += y;
        }
        if (lane == 63) wsum[wid] = x;
        __syncthreads();
        int pre = run_s;
        #pragma unroll
        for (int w = 0; w < 4; ++w) { if (w < wid) pre += wsum[w]; }
        if (i < NB) bsum[i] = pre + x - v;
        __syncthreads();
        if (t == 0) run_s += wsum[0] + wsum[1] + wsum[2] + wsum[3];
        __syncthreads();
    }
    if (t == 0) offs[Nn] = run_s;
}

__global__ __launch_bounds__(256) void scan_p3(const int* __restrict__ cnt,
                                               const int* __restrict__ bsum,
                                               int* __restrict__ offs,
                                               int* __restrict__ cursor, int Nn) {
    __shared__ int wsum[4];
    const int t = threadIdx.x, b = blockIdx.x, lane = t & 63, wid = t >> 6;
    int i = b * 256 + t;
    int v = (i < Nn) ? cnt[i] : 0;
    int x = v;
    #pragma unroll
    for (int o = 1; o < 64; o <<= 1) {
        int y = __shfl_up(x, o);
        if (lane >= o) x += y;
    }
    if (lane == 63) wsum[wid] = x;
    __syncthreads();
    int pre = bsum[b];
    #pragma unroll
    for (int w = 0; w < 4; ++w) { if (w < wid) pre += wsum[w]; }
    if (i < Nn) {
        int excl = pre + x - v;
        offs[i] = excl;
        cursor[i] = excl;
    }
}

__global__ void scatter_kernel(const int* __restrict__ src, const int* __restrict__ dst,
                               int* __restrict__ cursor, int* __restrict__ col, int E) {
    int e = blockIdx.x * 256 + threadIdx.x;
    if (e < E) {
        int p = atomicAdd(&cursor[dst[e]], 1);
        col[p] = src[e];
    }
}

// ---------------------------------------------------------------------------
// Weight prep: square W[k][n] -> bf16 transposed [n][k] (32768-short slots,
// hi only — lo slots unused). Wp2 padded [48][128]. Wg panels [16][128].
// ---------------------------------------------------------------------------
__global__ void prep_weights(const float* __restrict__ Wt, const float* __restrict__ W1,
                             const float* __restrict__ W2, const float* __restrict__ Wp1,
                             const float* __restrict__ Wp2, const float* __restrict__ Wg,
                             u16* __restrict__ wbuf, int L) {
    const int m = blockIdx.y;
    const int id = blockIdx.x * 256 + threadIdx.x;
    const int nsq = 3 * L + 1;
    if (m < nsq) {
        u16* base = wbuf + (size_t)m * 32768;
        const float* src = (m < L) ? Wt + m * 16384
                         : (m < 2 * L) ? W1 + (m - L) * 16384
                         : (m < 3 * L) ? W2 + (m - 2 * L) * 16384
                         : Wp1;
        int n = id >> 7, k = id & 127;
        base[n * 128 + k] = bf16_of(src[k * 128 + n]);
    } else if (m == nsq) {               // Wp2
        if (id >= 48 * 128) return;
        u16* base = wbuf + (size_t)m * 32768;
        int n = id >> 7, k = id & 127;
        base[n * 128 + k] = bf16_of((n < CLS) ? Wp2[k * CLS + n] : 0.f);
    } else {                             // Wg panel
        int gi = m - (nsq + 1);
        if (id >= 2048) return;
        u16* base = wbuf + (size_t)(nsq + 1) * 32768 + (size_t)gi * 4096;
        base[id] = bf16_of((id < 128) ? Wg[gi * 128 + id] : 0.f);
    }
}

// ---------------------------------------------------------------------------
// GEMM building blocks. Block tile 64 rows x 128 cols, K=128, 4 waves.
// COLUMN-split: wave w owns cols [32w, 32w+32); 8 single-bf16 B-fragments in
// registers for the whole GEMM -> 8 MFMAs per B-load, no re-fetch.
// A-frag: A[m=l16][k=quad*8+j]; C/D: row=rt*16+quad*4+reg, col=l16 (measured).
// ---------------------------------------------------------------------------
__device__ __forceinline__ void stage_f32(const float* __restrict__ A, int m0, int M,
                                          u16* As, int t) {
    #pragma unroll
    for (int i = 0; i < 8; ++i) {
        int id = i * 256 + t;
        int row = id >> 5, c4 = id & 31;
        float4 v = make_float4(0.f, 0.f, 0.f, 0.f);
        if (m0 + row < M) v = ((const float4*)A)[(size_t)(m0 + row) * 32 + c4];
        ushort4v hh = {bf16_of(v.x), bf16_of(v.y), bf16_of(v.z), bf16_of(v.w)};
        *(ushort4v*)(&As[row * AS_STRIDE + c4 * 4]) = hh;
    }
}

__device__ __forceinline__ void stage_bf16(const u16* __restrict__ A, int m0, int M,
                                           u16* As, int t) {
    #pragma unroll
    for (int i = 0; i < 4; ++i) {
        int id = i * 256 + t;
        int row = id >> 4, c8 = id & 15;
        short8 v = {0, 0, 0, 0, 0, 0, 0, 0};
        if (m0 + row < M) v = ((const short8*)A)[(size_t)(m0 + row) * 16 + c8];
        *(short8*)(&As[row * AS_STRIDE + c8 * 8]) = v;
    }
}

struct Bfrags { short8 h[2][4]; };   // [ct][kc], 32 VGPRs (single bf16, no lo)

__device__ __forceinline__ void load_B(const u16* __restrict__ Bh,
                                       int ct0, int l16, int quad, Bfrags& f) {
    #pragma unroll
    for (int c = 0; c < 2; ++c)
        #pragma unroll
        for (int kc = 0; kc < 4; ++kc) {
            int boff = ((ct0 + c) * 16 + l16) * 128 + kc * 32 + quad * 8;
            f.h[c][kc] = *(const short8*)(&Bh[boff]);
        }
}

__device__ __forceinline__ void gemm_ct2(const u16* As, const Bfrags& f, int l16, int quad,
                                         floatx4 (&acc)[4][2]) {
    #pragma unroll
    for (int kc = 0; kc < 4; ++kc) {
        short8 a[4];
        #pragma unroll
        for (int rt = 0; rt < 4; ++rt)
            a[rt] = *(const short8*)(&As[(rt * 16 + l16) * AS_STRIDE + kc * 32 + quad * 8]);
        #pragma unroll
        for (int rt = 0; rt < 4; ++rt)
            #pragma unroll
            for (int c = 0; c < 2; ++c)
                acc[rt][c] = __builtin_amdgcn_mfma_f32_16x16x32_bf16(a[rt], f.h[c][kc], acc[rt][c], 0, 0, 0);
    }
}

#define ZERO_ACC(acc) { _Pragma("unroll") for (int rt = 0; rt < 4; ++rt) \
    { acc[rt][0] = (floatx4){0.f,0.f,0.f,0.f}; acc[rt][1] = (floatx4){0.f,0.f,0.f,0.f}; } }

// gate panel (16x128, only col 0 nonzero) on wave 0; writes gate rows
__device__ __forceinline__ void gate_panel(const u16* As, const u16* __restrict__ Gh,
                                           const float* __restrict__ bg,
                                           float* __restrict__ gate,
                                           int m0, int M, int l16, int quad) {
    floatx4 gacc[4];
    #pragma unroll
    for (int rt = 0; rt < 4; ++rt) gacc[rt] = (floatx4){0.f, 0.f, 0.f, 0.f};
    #pragma unroll
    for (int kc = 0; kc < 4; ++kc) {
        int boff = l16 * 128 + kc * 32 + quad * 8;
        short8 gh = *(const short8*)(&Gh[boff]);
        #pragma unroll
        for (int rt = 0; rt < 4; ++rt) {
            short8 a = *(const short8*)(&As[(rt * 16 + l16) * AS_STRIDE + kc * 32 + quad * 8]);
            gacc[rt] = __builtin_amdgcn_mfma_f32_16x16x32_bf16(a, gh, gacc[rt], 0, 0, 0);
        }
    }
    if (l16 == 0) {
        float b0 = bg[0];
        #pragma unroll
        for (int rt = 0; rt < 4; ++rt)
            #pragma unroll
            for (int reg = 0; reg < 4; ++reg) {
                int row = m0 + rt * 16 + quad * 4 + reg;
                if (row < M) gate[row] = gacc[rt][reg] + b0;
            }
    }
}

// ---------------------------------------------------------------------------
// Layer-0 entry: ht(bf16) = x @ Wt + bt ; gate = x @ Wg + bg   (x is f32)
// ---------------------------------------------------------------------------
__global__ __launch_bounds__(256, 3) void gemm_gate_kernel(
    const float* __restrict__ Af,
    const u16* __restrict__ Gh, const float* __restrict__ bg,
    const u16* __restrict__ Bh, const float* __restrict__ bt,
    u16* __restrict__ ht, float* __restrict__ gate, int M) {
    __shared__ __align__(16) u16 As[64 * AS_STRIDE];
    const int t = threadIdx.x, m0 = blockIdx.x * 64;
    const int w = t >> 6, lane = t & 63, l16 = lane & 15, quad = lane >> 4, ct0 = w * 2;
    Bfrags f;
    load_B(Bh, ct0, l16, quad, f);      // in flight during staging
    stage_f32(Af, m0, M, As, t);
    __syncthreads();
    floatx4 acc[4][2];
    ZERO_ACC(acc);
    gemm_ct2(As, f, l16, quad, acc);
    if (w == 0) gate_panel(As, Gh, bg, gate, m0, M, l16, quad);
    #pragma unroll
    for (int c = 0; c < 2; ++c) {
        int cc = (ct0 + c) * 16 + l16;
        float b = bt[cc];
        #pragma unroll
        for (int rt = 0; rt < 4; ++rt)
            #pragma unroll
            for (int reg = 0; reg < 4; ++reg) {
                int row = m0 + rt * 16 + quad * 4 + reg;
                if (row < M) ht[(size_t)row * 128 + cc] = bf16_of(acc[rt][c][reg] + b);
            }
    }
}

// ---------------------------------------------------------------------------
// Attention aggregation: one wave per dst node; ht rows bf16; out packed bf16.
// Edge loop unrolled x8 for memory-level parallelism (latency-bound gather).
// ---------------------------------------------------------------------------
__global__ __launch_bounds__(256) void agg_kernel(const float* __restrict__ gate,
                                                  const u32* __restrict__ ht32,
                                                  const int* __restrict__ offs,
                                                  const int* __restrict__ col,
                                                  u32* __restrict__ aggb, int Nn) {
    int gt = blockIdx.x * 256 + threadIdx.x;
    int n = gt >> 6, lane = gt & 63;
    if (n >= Nn) return;
    int beg = offs[n], end = offs[n + 1];
    float gs = gate[n];
    float m = gs;
    for (int e = beg + lane; e < end; e += 64) m = fmaxf(m, gate[col[e]]);
    #pragma unroll
    for (int o = 32; o; o >>= 1) m = fmaxf(m, __shfl_xor(m, o));
    float wself = __expf(gs - m);
    float denom0 = wself, denom1 = 0.f;
    u32 sv = ht32[(size_t)n * 64 + lane];
    float a0 = wself * blo(sv), a1 = wself * bhi(sv);
    float b0 = 0.f, b1 = 0.f;
    int e = beg;
    for (; e + 8 <= end; e += 8) {
        int c[8];
        #pragma unroll
        for (int j = 0; j < 8; ++j) c[j] = col[e + j];
        float g[8];
        #pragma unroll
        for (int j = 0; j < 8; ++j) g[j] = gate[c[j]];
        u32 v[8];
        #pragma unroll
        for (int j = 0; j < 8; ++j) v[j] = ht32[(size_t)c[j] * 64 + lane];
        float wj[8];
        #pragma unroll
        for (int j = 0; j < 8; ++j) wj[j] = __expf(g[j] - m);
        denom0 += (wj[0] + wj[1]) + (wj[2] + wj[3]);
        denom1 += (wj[4] + wj[5]) + (wj[6] + wj[7]);
        #pragma unroll
        for (int j = 0; j < 4; ++j) {
            a0 += wj[j] * blo(v[j]);
            a1 += wj[j] * bhi(v[j]);
        }
        #pragma unroll
        for (int j = 4; j < 8; ++j) {
            b0 += wj[j] * blo(v[j]);
            b1 += wj[j] * bhi(v[j]);
        }
    }
    for (; e < end; ++e) {
        int c = col[e];
        float w = __expf(gate[c] - m);
        u32 v = ht32[(size_t)c * 64 + lane];
        denom0 += w;
        a0 += w * blo(v);
        a1 += w * bhi(v);
    }
    float inv = 1.0f / (denom0 + denom1);
    float r0 = (a0 + b0) * inv, r1 = (a1 + b1) * inv;
    aggb[(size_t)n * 64 + lane] = (u32)bf16_of(r0) | ((u32)bf16_of(r1) << 16);
}

// ---------------------------------------------------------------------------
// Mid-layer mega kernel: agg -> h (W1/BN/hswish, W2/hswish) -> next layer's
// ht = h @ Wt' + bt' and gate = h @ Wg' + bg'. h never touches global.
// ---------------------------------------------------------------------------
__global__ __launch_bounds__(256, 3) void layer_mid_kernel(
    const u16* __restrict__ A,
    const u16* __restrict__ B1h, const float* __restrict__ b1,
    const float* __restrict__ bng, const float* __restrict__ bnb,
    const float* __restrict__ bnm, const float* __restrict__ bnv,
    const u16* __restrict__ B2h, const float* __restrict__ b2,
    const u16* __restrict__ Wth, const float* __restrict__ bt,
    const u16* __restrict__ Gh, const float* __restrict__ bg,
    u16* __restrict__ htb, float* __restrict__ gate, int M) {
    __shared__ __align__(16) u16 As[64 * AS_STRIDE];
    __shared__ __align__(16) u16 Zs[64 * AS_STRIDE];
    const int t = threadIdx.x, m0 = blockIdx.x * 64;
    const int w = t >> 6, lane = t & 63, l16 = lane & 15, quad = lane >> 4, ct0 = w * 2;
    Bfrags f;
    load_B(B1h, ct0, l16, quad, f);     // in flight during staging
    stage_bf16(A, m0, M, As, t);
    __syncthreads();
    floatx4 acc[4][2];
    ZERO_ACC(acc);
    gemm_ct2(As, f, l16, quad, acc);
    // z = hswish(BN(acc+b1)) -> Zs
    #pragma unroll
    for (int c = 0; c < 2; ++c) {
        int cc = (ct0 + c) * 16 + l16;
        float sc = bng[cc] * rsqrtf(bnv[cc] + BN_EPS);
        float sh = bnb[cc] - bnm[cc] * sc;
        float bb = b1[cc];
        #pragma unroll
        for (int rt = 0; rt < 4; ++rt)
            #pragma unroll
            for (int reg = 0; reg < 4; ++reg) {
                int r = rt * 16 + quad * 4 + reg;
                Zs[r * AS_STRIDE + cc] = bf16_of(hswish((acc[rt][c][reg] + bb) * sc + sh));
            }
    }
    load_B(B2h, ct0, l16, quad, f);
    __syncthreads();            // Zs complete; As reads complete -> As reusable
    ZERO_ACC(acc);
    gemm_ct2(Zs, f, l16, quad, acc);
    // h = hswish(acc+b2) -> As (bf16)
    #pragma unroll
    for (int c = 0; c < 2; ++c) {
        int cc = (ct0 + c) * 16 + l16;
        float b = b2[cc];
        #pragma unroll
        for (int rt = 0; rt < 4; ++rt)
            #pragma unroll
            for (int reg = 0; reg < 4; ++reg) {
                int r = rt * 16 + quad * 4 + reg;
                As[r * AS_STRIDE + cc] = bf16_of(hswish(acc[rt][c][reg] + b));
            }
    }
    load_B(Wth, ct0, l16, quad, f);
    __syncthreads();            // h tile complete in As
    ZERO_ACC(acc);
    gemm_ct2(As, f, l16, quad, acc);
    if (w == 0) gate_panel(As, Gh, bg, gate, m0, M, l16, quad);
    #pragma unroll
    for (int c = 0; c < 2; ++c) {
        int cc = (ct0 + c) * 16 + l16;
        float b = bt[cc];
        #pragma unroll
        for (int rt = 0; rt < 4; ++rt)
            #pragma unroll
            for (int reg = 0; reg < 4; ++reg) {
                int row = m0 + rt * 16 + quad * 4 + reg;
                if (row < M) htb[(size_t)row * 128 + cc] = bf16_of(acc[rt][c][reg] + b);
            }
    }
}

// ---------------------------------------------------------------------------
// Final-layer mega kernel: agg -> h -> head: z' = hswish(h@Wp1+bp1),
// logits = z'@Wp2+bp2, out = log_softmax(logits).
// ---------------------------------------------------------------------------
__global__ __launch_bounds__(256, 3) void layer_final_kernel(
    const u16* __restrict__ A,
    const u16* __restrict__ B1h, const float* __restrict__ b1,
    const float* __restrict__ bng, const float* __restrict__ bnb,
    const float* __restrict__ bnm, const float* __restrict__ bnv,
    const u16* __restrict__ B2h, const float* __restrict__ b2,
    const u16* __restrict__ P1h, const float* __restrict__ bp1,
    const u16* __restrict__ P2h, const float* __restrict__ bp2,
    float* __restrict__ out, int M) {
    __shared__ __align__(16) u16 As[64 * AS_STRIDE];
    __shared__ __align__(16) u16 Zs[64 * AS_STRIDE];
    const int t = threadIdx.x, m0 = blockIdx.x * 64;
    const int w = t >> 6, lane = t & 63, l16 = lane & 15, quad = lane >> 4, ct0 = w * 2;
    Bfrags f;
    load_B(B1h, ct0, l16, quad, f);
    stage_bf16(A, m0, M, As, t);
    __syncthreads();
    floatx4 acc[4][2];
    ZERO_ACC(acc);
    gemm_ct2(As, f, l16, quad, acc);
    #pragma unroll
    for (int c = 0; c < 2; ++c) {
        int cc = (ct0 + c) * 16 + l16;
        float sc = bng[cc] * rsqrtf(bnv[cc] + BN_EPS);
        float sh = bnb[cc] - bnm[cc] * sc;
        float bb = b1[cc];
        #pragma unroll
        for (int rt = 0; rt < 4; ++rt)
            #pragma unroll
            for (int reg = 0; reg < 4; ++reg) {
                int r = rt * 16 + quad * 4 + reg;
                Zs[r * AS_STRIDE + cc] = bf16_of(hswish((acc[rt][c][reg] + bb) * sc + sh));
            }
    }
    load_B(B2h, ct0, l16, quad, f);
    __syncthreads();
    ZERO_ACC(acc);
    gemm_ct2(Zs, f, l16, quad, acc);
    // h = hswish(acc+b2) -> As
    #pragma unroll
    for (int c = 0; c < 2; ++c) {
        int cc = (ct0 + c) * 16 + l16;
        float b = b2[cc];
        #pragma unroll
        for (int rt = 0; rt < 4; ++rt)
            #pragma unroll
            for (int reg = 0; reg < 4; ++reg) {
                int r = rt * 16 + quad * 4 + reg;
                As[r * AS_STRIDE + cc] = bf16_of(hswish(acc[rt][c][reg] + b));
            }
    }
    load_B(P1h, ct0, l16, quad, f);
    __syncthreads();
    ZERO_ACC(acc);
    gemm_ct2(As, f, l16, quad, acc);
    // z' = hswish(acc+bp1) -> Zs
    #pragma unroll
    for (int c = 0; c < 2; ++c) {
        int cc = (ct0 + c) * 16 + l16;
        float bb = bp1[cc];
        #pragma unroll
        for (int rt = 0; rt < 4; ++rt)
            #pragma unroll
            for (int reg = 0; reg < 4; ++reg) {
                int r = rt * 16 + quad * 4 + reg;
                Zs[r * AS_STRIDE + cc] = bf16_of(hswish(acc[rt][c][reg] + bb));
            }
    }
    __syncthreads();
    // head GEMM2 row-split: wave w owns rows [16w,16w+16), all 3 col-tiles
    const int wr0 = w * 16;
    floatx4 acc2[3];
    #pragma unroll
    for (int ct = 0; ct < 3; ++ct) acc2[ct] = (floatx4){0.f, 0.f, 0.f, 0.f};
    #pragma unroll
    for (int kc = 0; kc < 4; ++kc) {
        short8 a = *(const short8*)(&Zs[(wr0 + l16) * AS_STRIDE + kc * 32 + quad * 8]);
        #pragma unroll
        for (int ct = 0; ct < 3; ++ct) {
            int boff = (ct * 16 + l16) * 128 + kc * 32 + quad * 8;
            short8 bh = *(const short8*)(&P2h[boff]);
            acc2[ct] = __builtin_amdgcn_mfma_f32_16x16x32_bf16(a, bh, acc2[ct], 0, 0, 0);
        }
    }
    #pragma unroll
    for (int reg = 0; reg < 4; ++reg) {
        float v[3];
        #pragma unroll
        for (int ct = 0; ct < 3; ++ct) {
            int c = ct * 16 + l16;
            v[ct] = (c < CLS) ? acc2[ct][reg] + bp2[c] : -INFINITY;
        }
        float mx = fmaxf(fmaxf(v[0], v[1]), v[2]);
        #pragma unroll
        for (int o = 1; o < 16; o <<= 1) mx = fmaxf(mx, __shfl_xor(mx, o));
        float s = 0.f;
        #pragma unroll
        for (int ct = 0; ct < 3; ++ct) s += (v[ct] > -INFINITY) ? __expf(v[ct] - mx) : 0.f;
        #pragma unroll
        for (int o = 1; o < 16; o <<= 1) s += __shfl_xor(s, o);
        float lse = mx + __logf(s);
        int row = m0 + wr0 + quad * 4 + reg;
        if (row < M) {
            #pragma unroll
            for (int ct = 0; ct < 3; ++ct) {
                int c = ct * 16 + l16;
                if (c < CLS) out[(size_t)row * CLS + c] = v[ct] - lse;
            }
        }
    }
}

// ---------------------------------------------------------------------------
extern "C" void kernel_launch(void* const* d_in, const int* in_sizes, int n_in,
                              void* d_out, int out_size, void* d_ws, size_t ws_size,
                              hipStream_t stream) {
    const float* x   = (const float*)d_in[0];
    const int*   src = (const int*)d_in[1];
    const int*   dst = (const int*)d_in[2];
    const float* Wg  = (const float*)d_in[3];
    const float* bg  = (const float*)d_in[4];
    const float* Wt  = (const float*)d_in[5];
    const float* bt  = (const float*)d_in[6];
    const float* W1  = (const float*)d_in[7];
    const float* b1  = (const float*)d_in[8];
    const float* bng = (const float*)d_in[9];
    const float* bnb = (const float*)d_in[10];
    const float* bnm = (const float*)d_in[11];
    const float* bnv = (const float*)d_in[12];
    const float* W2  = (const float*)d_in[13];
    const float* b2  = (const float*)d_in[14];
    const float* Wp1 = (const float*)d_in[15];
    const float* bp1 = (const float*)d_in[16];
    const float* Wp2 = (const float*)d_in[17];
    const float* bp2 = (const float*)d_in[18];
    float* out = (float*)d_out;

    const int N = in_sizes[0] / FD;
    const int E = in_sizes[1];
    const int L = in_sizes[3] / FD;
    const int nsq = 3 * L + 1;
    const int NB = (N + 255) / 256;

    u16* htb    = (u16*)d_ws;                          // N*128 bf16
    u16* aggb   = htb + (size_t)N * FD;                // N*128 bf16 (packed u32/lane)
    float* gate = (float*)(aggb + (size_t)N * FD);     // N
    u16* wbuf   = (u16*)(gate + N);
    size_t wslots = (size_t)(nsq + 1) * 32768 + (size_t)L * 4096;
    int* counts = (int*)(wbuf + wslots);
    int* offs   = counts + N;
    int* cursor = offs + (N + 1);
    int* col    = cursor + N;
    int* bsum   = col + E;

    // CSR build + weight prep (static inputs, ws re-poisoned each call)
    hipMemsetAsync(counts, 0, N * sizeof(int), stream);
    hist_kernel<<<(E + 255) / 256, 256, 0, stream>>>(dst, counts, E);
    prep_weights<<<dim3(64, nsq + 1 + L), 256, 0, stream>>>(Wt, W1, W2, Wp1, Wp2, Wg, wbuf, L);
    scan_p1<<<NB, 256, 0, stream>>>(counts, bsum, N);
    scan_p2<<<1, 256, 0, stream>>>(bsum, NB, offs, N);
    scan_p3<<<NB, 256, 0, stream>>>(counts, bsum, offs, cursor, N);
    scatter_kernel<<<(E + 255) / 256, 256, 0, stream>>>(src, dst, cursor, col, E);

    const int grid_g = (N + 63) / 64;
    const int wave_grid = (N + 3) / 4;

    u16* gp0 = wbuf + (size_t)(nsq + 1) * 32768;
    u16* wt0 = wbuf;
    gemm_gate_kernel<<<grid_g, 256, 0, stream>>>(x, gp0, bg, wt0, bt, htb, gate, N);
    for (int i = 0; i < L; ++i) {
        agg_kernel<<<wave_grid, 256, 0, stream>>>(gate, (const u32*)htb,
                                                  offs, col, (u32*)aggb, N);
        u16* w1 = wbuf + (size_t)(L + i) * 32768;
        u16* w2 = wbuf + (size_t)(2 * L + i) * 32768;
        if (i < L - 1) {
            u16* wtn = wbuf + (size_t)(i + 1) * 32768;
            u16* gpn = wbuf + (size_t)(nsq + 1) * 32768 + (size_t)(i + 1) * 4096;
            layer_mid_kernel<<<grid_g, 256, 0, stream>>>(aggb,
                w1, b1 + i * FD,
                bng + i * FD, bnb + i * FD, bnm + i * FD, bnv + i * FD,
                w2, b2 + i * FD,
                wtn, bt + (i + 1) * FD,
                gpn, bg + (i + 1),
                htb, gate, N);
        } else {
            u16* wp1 = wbuf + (size_t)(3 * L) * 32768;
            u16* wp2 = wbuf + (size_t)nsq * 32768;
            layer_final_kernel<<<grid_g, 256, 0, stream>>>(aggb,
                w1, b1 + i * FD,
                bng + i * FD, bnb + i * FD, bnm + i * FD, bnv + i * FD,
                w2, b2 + i * FD,
                wp1, bp1,
                wp2, bp2,
                out, N);
        }
    }
}

// Round 10
// 421.141 us; speedup vs baseline: 1.3280x; 1.1029x over previous
//
#include <hip/hip_runtime.h>
#include <math.h>

#define FD 128
#define CLS 40
#define BN_EPS 1e-5f
#define AS_STRIDE 136   // ushort stride: 272 B rows, 16B-aligned, 2-way bank aliasing only
// TM=64 (R8's TM=32 regressed: B-reuse per block beats occupancy). Single-bf16
// B panels (no lo term): absmax unchanged at 0.0156 — activation rounding dominates.

typedef short short8 __attribute__((ext_vector_type(8)));
typedef float floatx4 __attribute__((ext_vector_type(4)));
typedef unsigned short ushort4v __attribute__((ext_vector_type(4)));
typedef unsigned short u16;
typedef unsigned int u32;

__device__ __forceinline__ u16 bf16_of(float v) {
    unsigned int u = __float_as_uint(v);
    unsigned int r = u + 0x7FFFu + ((u >> 16) & 1u);   // RNE
    return (u16)(r >> 16);
}
__device__ __forceinline__ float bf16f(u16 h) {
    return __uint_as_float(((unsigned int)h) << 16);
}
__device__ __forceinline__ float blo(u32 v) { return __uint_as_float(v << 16); }
__device__ __forceinline__ float bhi(u32 v) { return __uint_as_float(v & 0xFFFF0000u); }
__device__ __forceinline__ float hswish(float x) {
    return x * fminf(fmaxf(x + 3.0f, 0.0f), 6.0f) * (1.0f / 6.0f);
}

// ---------------------------------------------------------------------------
// CSR build: hist(+rank) -> 3-pass parallel exclusive scan -> rank-scatter
// hist returns each edge's arrival order as its rank within its dst bucket,
// so scatter needs NO atomics (R9: scatter was 44 us, atomic+random bound).
// ---------------------------------------------------------------------------
__global__ void hist_kernel(const int* __restrict__ dst, int* __restrict__ cnt,
                            int* __restrict__ rank, int E) {
    int e = blockIdx.x * 256 + threadIdx.x;
    if (e < E) rank[e] = atomicAdd(&cnt[dst[e]], 1);
}

__global__ __launch_bounds__(256) void scan_p1(const int* __restrict__ cnt,
                                               int* __restrict__ bsum, int Nn) {
    const int t = threadIdx.x, b = blockIdx.x;
    int i = b * 256 + t;
    int v = (i < Nn) ? cnt[i] : 0;
    #pragma unroll
    for (int o = 32; o; o >>= 1) v += __shfl_xor(v, o);
    __shared__ int ws[4];
    if ((t & 63) == 0) ws[t >> 6] = v;
    __syncthreads();
    if (t == 0) bsum[b] = ws[0] + ws[1] + ws[2] + ws[3];
}

__global__ __launch_bounds__(256) void scan_p2(int* __restrict__ bsum, int NB,
                                               int* __restrict__ offs, int Nn) {
    __shared__ int wsum[4];
    __shared__ int run_s;
    const int t = threadIdx.x, lane = t & 63, wid = t >> 6;
    if (t == 0) run_s = 0;
    __syncthreads();
    for (int base = 0; base < NB; base += 256) {
        int i = base + t;
        int v = (i < NB) ? bsum[i] : 0;
        int x = v;
        #pragma unroll
        for (int o = 1; o < 64; o <<= 1) {
            int y = __shfl_up(x, o);
            if (lane >= o) x += y;
        }
        if (lane == 63) wsum[wid] = x;
        __syncthreads();
        int pre = run_s;
        #pragma unroll
        for (int w = 0; w < 4; ++w) { if (w < wid) pre += wsum[w]; }
        if (i < NB) bsum[i] = pre + x - v;
        __syncthreads();
        if (t == 0) run_s += wsum[0] + wsum[1] + wsum[2] + wsum[3];
        __syncthreads();
    }
    if (t == 0) offs[Nn] = run_s;
}

__global__ __launch_bounds__(256) void scan_p3(const int* __restrict__ cnt,
                                               const int* __restrict__ bsum,
                                               int* __restrict__ offs, int Nn) {
    __shared__ int wsum[4];
    const int t = threadIdx.x, b = blockIdx.x, lane = t & 63, wid = t >> 6;
    int i = b * 256 + t;
    int v = (i < Nn) ? cnt[i] : 0;
    int x = v;
    #pragma unroll
    for (int o = 1; o < 64; o <<= 1) {
        int y = __shfl_up(x, o);
        if (lane >= o) x += y;
    }
    if (lane == 63) wsum[wid] = x;
    __syncthreads();
    int pre = bsum[b];
    #pragma unroll
    for (int w = 0; w < 4; ++w) { if (w < wid) pre += wsum[w]; }
    if (i < Nn) offs[i] = pre + x - v;
}

__global__ void scatter_kernel(const int* __restrict__ src, const int* __restrict__ dst,
                               const int* __restrict__ offs, const int* __restrict__ rank,
                               int* __restrict__ col, int E) {
    int e = blockIdx.x * 256 + threadIdx.x;
    if (e < E) col[offs[dst[e]] + rank[e]] = src[e];
}

// ---------------------------------------------------------------------------
// Weight prep: square W[k][n] -> bf16 transposed [n][k] (32768-short slots,
// hi only). Wp2 padded [48][128]. Wg panels [16][128].
// ---------------------------------------------------------------------------
__global__ void prep_weights(const float* __restrict__ Wt, const float* __restrict__ W1,
                             const float* __restrict__ W2, const float* __restrict__ Wp1,
                             const float* __restrict__ Wp2, const float* __restrict__ Wg,
                             u16* __restrict__ wbuf, int L) {
    const int m = blockIdx.y;
    const int id = blockIdx.x * 256 + threadIdx.x;
    const int nsq = 3 * L + 1;
    if (m < nsq) {
        u16* base = wbuf + (size_t)m * 32768;
        const float* src = (m < L) ? Wt + m * 16384
                         : (m < 2 * L) ? W1 + (m - L) * 16384
                         : (m < 3 * L) ? W2 + (m - 2 * L) * 16384
                         : Wp1;
        int n = id >> 7, k = id & 127;
        base[n * 128 + k] = bf16_of(src[k * 128 + n]);
    } else if (m == nsq) {               // Wp2
        if (id >= 48 * 128) return;
        u16* base = wbuf + (size_t)m * 32768;
        int n = id >> 7, k = id & 127;
        base[n * 128 + k] = bf16_of((n < CLS) ? Wp2[k * CLS + n] : 0.f);
    } else {                             // Wg panel
        int gi = m - (nsq + 1);
        if (id >= 2048) return;
        u16* base = wbuf + (size_t)(nsq + 1) * 32768 + (size_t)gi * 4096;
        base[id] = bf16_of((id < 128) ? Wg[gi * 128 + id] : 0.f);
    }
}

// ---------------------------------------------------------------------------
// GEMM building blocks. Block tile 64 rows x 128 cols, K=128, 4 waves.
// COLUMN-split: wave w owns cols [32w, 32w+32); 8 single-bf16 B-fragments in
// registers for the whole GEMM -> 8 MFMAs per B-load, no re-fetch.
// A-frag: A[m=l16][k=quad*8+j]; C/D: row=rt*16+quad*4+reg, col=l16 (measured).
// ---------------------------------------------------------------------------
__device__ __forceinline__ void stage_f32(const float* __restrict__ A, int m0, int M,
                                          u16* As, int t) {
    #pragma unroll
    for (int i = 0; i < 8; ++i) {
        int id = i * 256 + t;
        int row = id >> 5, c4 = id & 31;
        float4 v = make_float4(0.f, 0.f, 0.f, 0.f);
        if (m0 + row < M) v = ((const float4*)A)[(size_t)(m0 + row) * 32 + c4];
        ushort4v hh = {bf16_of(v.x), bf16_of(v.y), bf16_of(v.z), bf16_of(v.w)};
        *(ushort4v*)(&As[row * AS_STRIDE + c4 * 4]) = hh;
    }
}

__device__ __forceinline__ void stage_bf16(const u16* __restrict__ A, int m0, int M,
                                           u16* As, int t) {
    #pragma unroll
    for (int i = 0; i < 4; ++i) {
        int id = i * 256 + t;
        int row = id >> 4, c8 = id & 15;
        short8 v = {0, 0, 0, 0, 0, 0, 0, 0};
        if (m0 + row < M) v = ((const short8*)A)[(size_t)(m0 + row) * 16 + c8];
        *(short8*)(&As[row * AS_STRIDE + c8 * 8]) = v;
    }
}

struct Bfrags { short8 h[2][4]; };   // [ct][kc], 32 VGPRs (single bf16)

__device__ __forceinline__ void load_B(const u16* __restrict__ Bh,
                                       int ct0, int l16, int quad, Bfrags& f) {
    #pragma unroll
    for (int c = 0; c < 2; ++c)
        #pragma unroll
        for (int kc = 0; kc < 4; ++kc) {
            int boff = ((ct0 + c) * 16 + l16) * 128 + kc * 32 + quad * 8;
            f.h[c][kc] = *(const short8*)(&Bh[boff]);
        }
}

__device__ __forceinline__ void gemm_ct2(const u16* As, const Bfrags& f, int l16, int quad,
                                         floatx4 (&acc)[4][2]) {
    #pragma unroll
    for (int kc = 0; kc < 4; ++kc) {
        short8 a[4];
        #pragma unroll
        for (int rt = 0; rt < 4; ++rt)
            a[rt] = *(const short8*)(&As[(rt * 16 + l16) * AS_STRIDE + kc * 32 + quad * 8]);
        #pragma unroll
        for (int rt = 0; rt < 4; ++rt)
            #pragma unroll
            for (int c = 0; c < 2; ++c)
                acc[rt][c] = __builtin_amdgcn_mfma_f32_16x16x32_bf16(a[rt], f.h[c][kc], acc[rt][c], 0, 0, 0);
    }
}

#define ZERO_ACC(acc) { _Pragma("unroll") for (int rt = 0; rt < 4; ++rt) \
    { acc[rt][0] = (floatx4){0.f,0.f,0.f,0.f}; acc[rt][1] = (floatx4){0.f,0.f,0.f,0.f}; } }

// gate panel (16x128, only col 0 nonzero) on wave 0; writes gate rows
__device__ __forceinline__ void gate_panel(const u16* As, const u16* __restrict__ Gh,
                                           const float* __restrict__ bg,
                                           float* __restrict__ gate,
                                           int m0, int M, int l16, int quad) {
    floatx4 gacc[4];
    #pragma unroll
    for (int rt = 0; rt < 4; ++rt) gacc[rt] = (floatx4){0.f, 0.f, 0.f, 0.f};
    #pragma unroll
    for (int kc = 0; kc < 4; ++kc) {
        int boff = l16 * 128 + kc * 32 + quad * 8;
        short8 gh = *(const short8*)(&Gh[boff]);
        #pragma unroll
        for (int rt = 0; rt < 4; ++rt) {
            short8 a = *(const short8*)(&As[(rt * 16 + l16) * AS_STRIDE + kc * 32 + quad * 8]);
            gacc[rt] = __builtin_amdgcn_mfma_f32_16x16x32_bf16(a, gh, gacc[rt], 0, 0, 0);
        }
    }
    if (l16 == 0) {
        float b0 = bg[0];
        #pragma unroll
        for (int rt = 0; rt < 4; ++rt)
            #pragma unroll
            for (int reg = 0; reg < 4; ++reg) {
                int row = m0 + rt * 16 + quad * 4 + reg;
                if (row < M) gate[row] = gacc[rt][reg] + b0;
            }
    }
}

// ---------------------------------------------------------------------------
// Layer-0 entry: ht(bf16) = x @ Wt + bt ; gate = x @ Wg + bg   (x is f32)
// ---------------------------------------------------------------------------
__global__ __launch_bounds__(256, 3) void gemm_gate_kernel(
    const float* __restrict__ Af,
    const u16* __restrict__ Gh, const float* __restrict__ bg,
    const u16* __restrict__ Bh, const float* __restrict__ bt,
    u16* __restrict__ ht, float* __restrict__ gate, int M) {
    __shared__ __align__(16) u16 As[64 * AS_STRIDE];
    const int t = threadIdx.x, m0 = blockIdx.x * 64;
    const int w = t >> 6, lane = t & 63, l16 = lane & 15, quad = lane >> 4, ct0 = w * 2;
    Bfrags f;
    load_B(Bh, ct0, l16, quad, f);      // in flight during staging
    stage_f32(Af, m0, M, As, t);
    __syncthreads();
    floatx4 acc[4][2];
    ZERO_ACC(acc);
    gemm_ct2(As, f, l16, quad, acc);
    if (w == 0) gate_panel(As, Gh, bg, gate, m0, M, l16, quad);
    #pragma unroll
    for (int c = 0; c < 2; ++c) {
        int cc = (ct0 + c) * 16 + l16;
        float b = bt[cc];
        #pragma unroll
        for (int rt = 0; rt < 4; ++rt)
            #pragma unroll
            for (int reg = 0; reg < 4; ++reg) {
                int row = m0 + rt * 16 + quad * 4 + reg;
                if (row < M) ht[(size_t)row * 128 + cc] = bf16_of(acc[rt][c][reg] + b);
            }
    }
}

// ---------------------------------------------------------------------------
// Attention aggregation: one wave per dst node; ht rows bf16; out packed bf16.
// Max-free softmax shifted by the SELF gate gs (softmax is shift-invariant;
// |g-gs| << 88 so exp is safe) -> removes the entire max-pass gather sweep.
// Edge loop unrolled x8 for memory-level parallelism.
// ---------------------------------------------------------------------------
__global__ __launch_bounds__(256) void agg_kernel(const float* __restrict__ gate,
                                                  const u32* __restrict__ ht32,
                                                  const int* __restrict__ offs,
                                                  const int* __restrict__ col,
                                                  u32* __restrict__ aggb, int Nn) {
    int gt = blockIdx.x * 256 + threadIdx.x;
    int n = gt >> 6, lane = gt & 63;
    if (n >= Nn) return;
    int beg = offs[n], end = offs[n + 1];
    float gs = gate[n];
    float denom0 = 1.0f, denom1 = 0.f;          // self: exp(gs-gs)=1
    u32 sv = ht32[(size_t)n * 64 + lane];
    float a0 = blo(sv), a1 = bhi(sv);
    float b0 = 0.f, b1 = 0.f;
    int e = beg;
    for (; e + 8 <= end; e += 8) {
        int c[8];
        #pragma unroll
        for (int j = 0; j < 8; ++j) c[j] = col[e + j];
        float g[8];
        #pragma unroll
        for (int j = 0; j < 8; ++j) g[j] = gate[c[j]];
        u32 v[8];
        #pragma unroll
        for (int j = 0; j < 8; ++j) v[j] = ht32[(size_t)c[j] * 64 + lane];
        float wj[8];
        #pragma unroll
        for (int j = 0; j < 8; ++j) wj[j] = __expf(g[j] - gs);
        denom0 += (wj[0] + wj[1]) + (wj[2] + wj[3]);
        denom1 += (wj[4] + wj[5]) + (wj[6] + wj[7]);
        #pragma unroll
        for (int j = 0; j < 4; ++j) {
            a0 += wj[j] * blo(v[j]);
            a1 += wj[j] * bhi(v[j]);
        }
        #pragma unroll
        for (int j = 4; j < 8; ++j) {
            b0 += wj[j] * blo(v[j]);
            b1 += wj[j] * bhi(v[j]);
        }
    }
    for (; e < end; ++e) {
        int c = col[e];
        float w = __expf(gate[c] - gs);
        u32 v = ht32[(size_t)c * 64 + lane];
        denom0 += w;
        a0 += w * blo(v);
        a1 += w * bhi(v);
    }
    float inv = 1.0f / (denom0 + denom1);
    float r0 = (a0 + b0) * inv, r1 = (a1 + b1) * inv;
    aggb[(size_t)n * 64 + lane] = (u32)bf16_of(r0) | ((u32)bf16_of(r1) << 16);
}

// ---------------------------------------------------------------------------
// Mid-layer mega kernel: agg -> h (W1/BN/hswish, W2/hswish) -> next layer's
// ht = h @ Wt' + bt' and gate = h @ Wg' + bg'. h never touches global.
// ---------------------------------------------------------------------------
__global__ __launch_bounds__(256, 3) void layer_mid_kernel(
    const u16* __restrict__ A,
    const u16* __restrict__ B1h, const float* __restrict__ b1,
    const float* __restrict__ bng, const float* __restrict__ bnb,
    const float* __restrict__ bnm, const float* __restrict__ bnv,
    const u16* __restrict__ B2h, const float* __restrict__ b2,
    const u16* __restrict__ Wth, const float* __restrict__ bt,
    const u16* __restrict__ Gh, const float* __restrict__ bg,
    u16* __restrict__ htb, float* __restrict__ gate, int M) {
    __shared__ __align__(16) u16 As[64 * AS_STRIDE];
    __shared__ __align__(16) u16 Zs[64 * AS_STRIDE];
    const int t = threadIdx.x, m0 = blockIdx.x * 64;
    const int w = t >> 6, lane = t & 63, l16 = lane & 15, quad = lane >> 4, ct0 = w * 2;
    Bfrags f;
    load_B(B1h, ct0, l16, quad, f);     // in flight during staging
    stage_bf16(A, m0, M, As, t);
    __syncthreads();
    floatx4 acc[4][2];
    ZERO_ACC(acc);
    gemm_ct2(As, f, l16, quad, acc);
    // z = hswish(BN(acc+b1)) -> Zs
    #pragma unroll
    for (int c = 0; c < 2; ++c) {
        int cc = (ct0 + c) * 16 + l16;
        float sc = bng[cc] * rsqrtf(bnv[cc] + BN_EPS);
        float sh = bnb[cc] - bnm[cc] * sc;
        float bb = b1[cc];
        #pragma unroll
        for (int rt = 0; rt < 4; ++rt)
            #pragma unroll
            for (int reg = 0; reg < 4; ++reg) {
                int r = rt * 16 + quad * 4 + reg;
                Zs[r * AS_STRIDE + cc] = bf16_of(hswish((acc[rt][c][reg] + bb) * sc + sh));
            }
    }
    load_B(B2h, ct0, l16, quad, f);
    __syncthreads();            // Zs complete; As reads complete -> As reusable
    ZERO_ACC(acc);
    gemm_ct2(Zs, f, l16, quad, acc);
    // h = hswish(acc+b2) -> As (bf16)
    #pragma unroll
    for (int c = 0; c < 2; ++c) {
        int cc = (ct0 + c) * 16 + l16;
        float b = b2[cc];
        #pragma unroll
        for (int rt = 0; rt < 4; ++rt)
            #pragma unroll
            for (int reg = 0; reg < 4; ++reg) {
                int r = rt * 16 + quad * 4 + reg;
                As[r * AS_STRIDE + cc] = bf16_of(hswish(acc[rt][c][reg] + b));
            }
    }
    load_B(Wth, ct0, l16, quad, f);
    __syncthreads();            // h tile complete in As
    ZERO_ACC(acc);
    gemm_ct2(As, f, l16, quad, acc);
    if (w == 0) gate_panel(As, Gh, bg, gate, m0, M, l16, quad);
    #pragma unroll
    for (int c = 0; c < 2; ++c) {
        int cc = (ct0 + c) * 16 + l16;
        float b = bt[cc];
        #pragma unroll
        for (int rt = 0; rt < 4; ++rt)
            #pragma unroll
            for (int reg = 0; reg < 4; ++reg) {
                int row = m0 + rt * 16 + quad * 4 + reg;
                if (row < M) htb[(size_t)row * 128 + cc] = bf16_of(acc[rt][c][reg] + b);
            }
    }
}

// ---------------------------------------------------------------------------
// Final-layer mega kernel: agg -> h -> head: z' = hswish(h@Wp1+bp1),
// logits = z'@Wp2+bp2, out = log_softmax(logits).
// ---------------------------------------------------------------------------
__global__ __launch_bounds__(256, 3) void layer_final_kernel(
    const u16* __restrict__ A,
    const u16* __restrict__ B1h, const float* __restrict__ b1,
    const float* __restrict__ bng, const float* __restrict__ bnb,
    const float* __restrict__ bnm, const float* __restrict__ bnv,
    const u16* __restrict__ B2h, const float* __restrict__ b2,
    const u16* __restrict__ P1h, const float* __restrict__ bp1,
    const u16* __restrict__ P2h, const float* __restrict__ bp2,
    float* __restrict__ out, int M) {
    __shared__ __align__(16) u16 As[64 * AS_STRIDE];
    __shared__ __align__(16) u16 Zs[64 * AS_STRIDE];
    const int t = threadIdx.x, m0 = blockIdx.x * 64;
    const int w = t >> 6, lane = t & 63, l16 = lane & 15, quad = lane >> 4, ct0 = w * 2;
    Bfrags f;
    load_B(B1h, ct0, l16, quad, f);
    stage_bf16(A, m0, M, As, t);
    __syncthreads();
    floatx4 acc[4][2];
    ZERO_ACC(acc);
    gemm_ct2(As, f, l16, quad, acc);
    #pragma unroll
    for (int c = 0; c < 2; ++c) {
        int cc = (ct0 + c) * 16 + l16;
        float sc = bng[cc] * rsqrtf(bnv[cc] + BN_EPS);
        float sh = bnb[cc] - bnm[cc] * sc;
        float bb = b1[cc];
        #pragma unroll
        for (int rt = 0; rt < 4; ++rt)
            #pragma unroll
            for (int reg = 0; reg < 4; ++reg) {
                int r = rt * 16 + quad * 4 + reg;
                Zs[r * AS_STRIDE + cc] = bf16_of(hswish((acc[rt][c][reg] + bb) * sc + sh));
            }
    }
    load_B(B2h, ct0, l16, quad, f);
    __syncthreads();
    ZERO_ACC(acc);
    gemm_ct2(Zs, f, l16, quad, acc);
    // h = hswish(acc+b2) -> As
    #pragma unroll
    for (int c = 0; c < 2; ++c) {
        int cc = (ct0 + c) * 16 + l16;
        float b = b2[cc];
        #pragma unroll
        for (int rt = 0; rt < 4; ++rt)
            #pragma unroll
            for (int reg = 0; reg < 4; ++reg) {
                int r = rt * 16 + quad * 4 + reg;
                As[r * AS_STRIDE + cc] = bf16_of(hswish(acc[rt][c][reg] + b));
            }
    }
    load_B(P1h, ct0, l16, quad, f);
    __syncthreads();
    ZERO_ACC(acc);
    gemm_ct2(As, f, l16, quad, acc);
    // z' = hswish(acc+bp1) -> Zs
    #pragma unroll
    for (int c = 0; c < 2; ++c) {
        int cc = (ct0 + c) * 16 + l16;
        float bb = bp1[cc];
        #pragma unroll
        for (int rt = 0; rt < 4; ++rt)
            #pragma unroll
            for (int reg = 0; reg < 4; ++reg) {
                int r = rt * 16 + quad * 4 + reg;
                Zs[r * AS_STRIDE + cc] = bf16_of(hswish(acc[rt][c][reg] + bb));
            }
    }
    __syncthreads();
    // head GEMM2 row-split: wave w owns rows [16w,16w+16), all 3 col-tiles
    const int wr0 = w * 16;
    floatx4 acc2[3];
    #pragma unroll
    for (int ct = 0; ct < 3; ++ct) acc2[ct] = (floatx4){0.f, 0.f, 0.f, 0.f};
    #pragma unroll
    for (int kc = 0; kc < 4; ++kc) {
        short8 a = *(const short8*)(&Zs[(wr0 + l16) * AS_STRIDE + kc * 32 + quad * 8]);
        #pragma unroll
        for (int ct = 0; ct < 3; ++ct) {
            int boff = (ct * 16 + l16) * 128 + kc * 32 + quad * 8;
            short8 bh = *(const short8*)(&P2h[boff]);
            acc2[ct] = __builtin_amdgcn_mfma_f32_16x16x32_bf16(a, bh, acc2[ct], 0, 0, 0);
        }
    }
    #pragma unroll
    for (int reg = 0; reg < 4; ++reg) {
        float v[3];
        #pragma unroll
        for (int ct = 0; ct < 3; ++ct) {
            int c = ct * 16 + l16;
            v[ct] = (c < CLS) ? acc2[ct][reg] + bp2[c] : -INFINITY;
        }
        float mx = fmaxf(fmaxf(v[0], v[1]), v[2]);
        #pragma unroll
        for (int o = 1; o < 16; o <<= 1) mx = fmaxf(mx, __shfl_xor(mx, o));
        float s = 0.f;
        #pragma unroll
        for (int ct = 0; ct < 3; ++ct) s += (v[ct] > -INFINITY) ? __expf(v[ct] - mx) : 0.f;
        #pragma unroll
        for (int o = 1; o < 16; o <<= 1) s += __shfl_xor(s, o);
        float lse = mx + __logf(s);
        int row = m0 + wr0 + quad * 4 + reg;
        if (row < M) {
            #pragma unroll
            for (int ct = 0; ct < 3; ++ct) {
                int c = ct * 16 + l16;
                if (c < CLS) out[(size_t)row * CLS + c] = v[ct] - lse;
            }
        }
    }
}

// ---------------------------------------------------------------------------
extern "C" void kernel_launch(void* const* d_in, const int* in_sizes, int n_in,
                              void* d_out, int out_size, void* d_ws, size_t ws_size,
                              hipStream_t stream) {
    const float* x   = (const float*)d_in[0];
    const int*   src = (const int*)d_in[1];
    const int*   dst = (const int*)d_in[2];
    const float* Wg  = (const float*)d_in[3];
    const float* bg  = (const float*)d_in[4];
    const float* Wt  = (const float*)d_in[5];
    const float* bt  = (const float*)d_in[6];
    const float* W1  = (const float*)d_in[7];
    const float* b1  = (const float*)d_in[8];
    const float* bng = (const float*)d_in[9];
    const float* bnb = (const float*)d_in[10];
    const float* bnm = (const float*)d_in[11];
    const float* bnv = (const float*)d_in[12];
    const float* W2  = (const float*)d_in[13];
    const float* b2  = (const float*)d_in[14];
    const float* Wp1 = (const float*)d_in[15];
    const float* bp1 = (const float*)d_in[16];
    const float* Wp2 = (const float*)d_in[17];
    const float* bp2 = (const float*)d_in[18];
    float* out = (float*)d_out;

    const int N = in_sizes[0] / FD;
    const int E = in_sizes[1];
    const int L = in_sizes[3] / FD;
    const int nsq = 3 * L + 1;
    const int NB = (N + 255) / 256;

    u16* htb    = (u16*)d_ws;                          // N*128 bf16
    u16* aggb   = htb + (size_t)N * FD;                // N*128 bf16 (packed u32/lane)
    float* gate = (float*)(aggb + (size_t)N * FD);     // N
    u16* wbuf   = (u16*)(gate + N);
    size_t wslots = (size_t)(nsq + 1) * 32768 + (size_t)L * 4096;
    int* counts = (int*)(wbuf + wslots);
    int* offs   = counts + N;
    int* rank   = offs + (N + 1);
    int* col    = rank + E;
    int* bsum   = col + E;

    // CSR build + weight prep (static inputs, ws re-poisoned each call)
    hipMemsetAsync(counts, 0, N * sizeof(int), stream);
    hist_kernel<<<(E + 255) / 256, 256, 0, stream>>>(dst, counts, rank, E);
    prep_weights<<<dim3(64, nsq + 1 + L), 256, 0, stream>>>(Wt, W1, W2, Wp1, Wp2, Wg, wbuf, L);
    scan_p1<<<NB, 256, 0, stream>>>(counts, bsum, N);
    scan_p2<<<1, 256, 0, stream>>>(bsum, NB, offs, N);
    scan_p3<<<NB, 256, 0, stream>>>(counts, bsum, offs, N);
    scatter_kernel<<<(E + 255) / 256, 256, 0, stream>>>(src, dst, offs, rank, col, E);

    const int grid_g = (N + 63) / 64;
    const int wave_grid = (N + 3) / 4;

    u16* gp0 = wbuf + (size_t)(nsq + 1) * 32768;
    u16* wt0 = wbuf;
    gemm_gate_kernel<<<grid_g, 256, 0, stream>>>(x, gp0, bg, wt0, bt, htb, gate, N);
    for (int i = 0; i < L; ++i) {
        agg_kernel<<<wave_grid, 256, 0, stream>>>(gate, (const u32*)htb,
                                                  offs, col, (u32*)aggb, N);
        u16* w1 = wbuf + (size_t)(L + i) * 32768;
        u16* w2 = wbuf + (size_t)(2 * L + i) * 32768;
        if (i < L - 1) {
            u16* wtn = wbuf + (size_t)(i + 1) * 32768;
            u16* gpn = wbuf + (size_t)(nsq + 1) * 32768 + (size_t)(i + 1) * 4096;
            layer_mid_kernel<<<grid_g, 256, 0, stream>>>(aggb,
                w1, b1 + i * FD,
                bng + i * FD, bnb + i * FD, bnm + i * FD, bnv + i * FD,
                w2, b2 + i * FD,
                wtn, bt + (i + 1) * FD,
                gpn, bg + (i + 1),
                htb, gate, N);
        } else {
            u16* wp1 = wbuf + (size_t)(3 * L) * 32768;
            u16* wp2 = wbuf + (size_t)nsq * 32768;
            layer_final_kernel<<<grid_g, 256, 0, stream>>>(aggb,
                w1, b1 + i * FD,
                bng + i * FD, bnb + i * FD, bnm + i * FD, bnv + i * FD,
                w2, b2 + i * FD,
                wp1, bp1,
                wp2, bp2,
                out, N);
        }
    }
}